// Round 9
// baseline (110.916 us; speedup 1.0000x reference)
//
#include <hip/hip_runtime.h>
#include <stdint.h>

typedef __bf16 bf16;
typedef __bf16 v8bf __attribute__((ext_vector_type(8)));
typedef float v4f __attribute__((ext_vector_type(4)));

#define T_SEQ   1024
#define D_MODEL 512
#define N_HEADS 8
#define D_HEAD  64
#define B_SZ    2
#define BH      (B_SZ * N_HEADS)     // 16
#define CHUNK   128
#define NCHUNK  (T_SEQ / CHUNK)      // 8
#define WN      (D_MODEL * D_MODEL)  // 262144

// async global->LDS, 16B per lane; LDS dest is wave-uniform base + lane*16
__device__ __forceinline__ void lds16(const void* g, void* l) {
    __builtin_amdgcn_global_load_lds(
        (const __attribute__((address_space(1))) uint32_t*)g,
        (__attribute__((address_space(3))) uint32_t*)l, 16, 0, 0);
}

// ------------------------------------------------- alpha partial sums
struct AlphaArgs { const float* w[4]; float* partial; };

__global__ __launch_bounds__(256) void k_alpha(AlphaArgs a) {
    const int bid = blockIdx.x, tid = threadIdx.x;
    const int mid = bid >> 6, blk = bid & 63;
    const float* __restrict__ W = a.w[mid];
    float sabs = 0.f;
    #pragma unroll
    for (int k = 0; k < 4; ++k) {
        float4 v = ((const float4*)W)[blk * 1024 + k * 256 + tid];
        sabs += fabsf(v.x) + fabsf(v.y) + fabsf(v.z) + fabsf(v.w);
    }
    __shared__ float red[256];
    red[tid] = sabs;
    __syncthreads();
    for (int s = 128; s > 0; s >>= 1) {
        if (tid < s) red[tid] += red[tid + s];
        __syncthreads();
    }
    if (tid == 0) a.partial[mid * 64 + blk] = red[0];
}

// per-wave reduce of 64 partials -> ternary scale s (all lanes get it)
__device__ __forceinline__ float alpha_scale(const float* partial, int mid) {
    const int lane = threadIdx.x & 63;
    float p = partial[mid * 64 + lane];
    #pragma unroll
    for (int w = 1; w < 64; w <<= 1) p += __shfl_xor(p, w);
    float alpha = p / (float)WN + 1e-12f;
    float e = fminf(4.f, fmaxf(-4.f, rintf(log2f(alpha))));
    return exp2f(e);
}

// ------------------------------------------------- f32-in 64x64 GEMM core
// C = A[64][512] @ ternary(B[64][512])^T. A cast f32->bf16, B quantized
// on the fly during staging (VGPR roundtrip + swizzled ds_write_b128).
// XOR swizzle: phys 16B chunk = logical ^ (row&7).
__device__ __forceinline__ void gemm64_f32(
        const float* __restrict__ Abase, const float* __restrict__ Bbase,
        float s, float inv_s, bf16* As, bf16* Bs, v4f acc[4]) {
    const int tid = threadIdx.x;
    const int wm = tid >> 6, lane = tid & 63;
    const int q = lane >> 4, r = lane & 15;
    const int r7 = r & 7;
    const int srow = tid >> 2;                // 64 rows, 4 thr/row

    for (int k0 = 0; k0 < 512; k0 += 64) {
        #pragma unroll
        for (int cp = 0; cp < 2; ++cp) {
            const int lc = (tid & 3) + cp * 4;        // logical 16B chunk
            const float* sa = Abase + srow * 512 + k0 + lc * 8;
            const float* sb = Bbase + srow * 512 + k0 + lc * 8;
            float4 a0 = *(const float4*)sa, a1 = *(const float4*)(sa + 4);
            float4 b0 = *(const float4*)sb, b1 = *(const float4*)(sb + 4);
            union { uint4 u; bf16 h[8]; } PA, PB;
            float av[8] = {a0.x, a0.y, a0.z, a0.w, a1.x, a1.y, a1.z, a1.w};
            float bv[8] = {b0.x, b0.y, b0.z, b0.w, b1.x, b1.y, b1.z, b1.w};
            #pragma unroll
            for (int j = 0; j < 8; ++j) {
                PA.h[j] = (bf16)av[j];
                float rr = rintf(bv[j] * inv_s);
                rr = fminf(1.f, fmaxf(-1.f, rr));
                PB.h[j] = (bf16)(rr * s);
            }
            const int pc = lc ^ (srow & 7);
            *(uint4*)((char*)As + srow * 128 + pc * 16) = PA.u;
            *(uint4*)((char*)Bs + srow * 128 + pc * 16) = PB.u;
        }
        __syncthreads();
        #pragma unroll
        for (int ss = 0; ss < 2; ++ss) {
            const int co = ((ss * 4 + q) ^ r7) * 8;
            v8bf ah = *(const v8bf*)&As[(wm * 16 + r) * 64 + co];
            v8bf bb[4];
            #pragma unroll
            for (int v = 0; v < 4; ++v)
                bb[v] = *(const v8bf*)&Bs[(v * 16 + r) * 64 + co];
            #pragma unroll
            for (int v = 0; v < 4; ++v)
                acc[v] = __builtin_amdgcn_mfma_f32_16x16x32_bf16(ah, bb[v], acc[v], 0, 0, 0);
        }
        __syncthreads();
    }
}

// bf16-A (lds16) + f32-quant-B variant, for oproj
__device__ __forceinline__ void gemm64_bf16A(
        const char* __restrict__ Ab, const float* __restrict__ Bbase,
        float s, float inv_s, bf16* As, bf16* Bs, v4f acc[4]) {
    const int tid = threadIdx.x;
    const int wm = tid >> 6, lane = tid & 63;
    const int q = lane >> 4, r = lane & 15;
    const int lrow = lane >> 3;
    const int schunk = (lane & 7) ^ lrow;     // swizzled source chunk for lds16
    const int r7 = r & 7;
    const int srow = tid >> 2;

    for (int k0 = 0; k0 < 512; k0 += 64) {
        #pragma unroll
        for (int j = 0; j < 2; ++j) {
            const int seg = wm * 2 + j;
            const int row = seg * 8 + lrow;
            const size_t goff = (size_t)row * 1024 + (size_t)k0 * 2 + schunk * 16;
            lds16(Ab + goff, (char*)As + (seg << 10));
        }
        #pragma unroll
        for (int cp = 0; cp < 2; ++cp) {
            const int lc = (tid & 3) + cp * 4;
            const float* sb = Bbase + srow * 512 + k0 + lc * 8;
            float4 b0 = *(const float4*)sb, b1 = *(const float4*)(sb + 4);
            union { uint4 u; bf16 h[8]; } PB;
            float bv[8] = {b0.x, b0.y, b0.z, b0.w, b1.x, b1.y, b1.z, b1.w};
            #pragma unroll
            for (int j = 0; j < 8; ++j) {
                float rr = rintf(bv[j] * inv_s);
                rr = fminf(1.f, fmaxf(-1.f, rr));
                PB.h[j] = (bf16)(rr * s);
            }
            const int pc = lc ^ (srow & 7);
            *(uint4*)((char*)Bs + srow * 128 + pc * 16) = PB.u;
        }
        __syncthreads();
        #pragma unroll
        for (int ss = 0; ss < 2; ++ss) {
            const int co = ((ss * 4 + q) ^ r7) * 8;
            v8bf ah = *(const v8bf*)&As[(wm * 16 + r) * 64 + co];
            v8bf bb[4];
            #pragma unroll
            for (int v = 0; v < 4; ++v)
                bb[v] = *(const v8bf*)&Bs[(v * 16 + r) * 64 + co];
            #pragma unroll
            for (int v = 0; v < 4; ++v)
                acc[v] = __builtin_amdgcn_mfma_f32_16x16x32_bf16(ah, bb[v], acc[v], 0, 0, 0);
        }
        __syncthreads();
    }
}

// ------------------------------------------------- fused QKV GEMM (+phi)
// tn 0..23: z = tn>>3 (0=Q,1=K,2=V), h = tn&7. B tile = W_z rows (tn&7)*64..
struct QkvArgs {
    const float* x; const float* w[3]; const float* partial;
    const float* table;
    bf16* phiqB; bf16* phikB; bf16* phikT; bf16* vbufT;
};

__global__ __launch_bounds__(256) void k_qkv(QkvArgs a) {
    __shared__ bf16 As[64 * 64] __attribute__((aligned(16)));
    __shared__ bf16 Bs[64 * 64] __attribute__((aligned(16)));
    __shared__ float tab[512];
    const int tid = threadIdx.x;
    const int tm = blockIdx.x, tn = blockIdx.y;
    const int z = tn >> 3;
    if (z < 2) { tab[tid] = a.table[tid]; tab[tid + 256] = a.table[tid + 256]; }

    const float s = alpha_scale(a.partial, z);
    const float inv_s = 1.f / s;

    v4f acc[4];
    #pragma unroll
    for (int v = 0; v < 4; ++v) acc[v] = (v4f){0.f, 0.f, 0.f, 0.f};

    gemm64_f32(a.x + (size_t)(tm * 64) * 512,
               a.w[z] + (size_t)((tn & 7) * 64) * 512,
               s, inv_s, As, Bs, acc);

    const int wm = tid >> 6, lane = tid & 63;
    const int q = lane >> 4, r = lane & 15;
    const int h = tn & 7;
    const int mb = tm * 64;
    const int b = mb >> 10, tpos0 = mb & 1023;     // 64 rows stay in one b
    const int bh = b * 8 + h;
    const int tpos = tpos0 + wm * 16 + q * 4;      // this thread's 4 tokens

    if (z < 2) {
        #pragma unroll
        for (int v = 0; v < 4; ++v) {
            const int d = v * 16 + r;
            union { uint2 pu; bf16 h4[4]; } P;
            #pragma unroll
            for (int i = 0; i < 4; ++i) {
                float val = acc[v][i];
                int i0 = (int)rintf(val / 0.1f) + 128;
                i0 = min(255, max(0, i0));
                int i1 = (int)rintf(val / 0.2f) + 128;
                i1 = min(255, max(0, i1));
                val = tab[i0] + tab[256 + i1];
                As[(wm * 16 + q * 4 + i) * 64 + d] = (bf16)val;
                P.h4[i] = (bf16)val;
            }
            if (z == 1)
                *(uint2*)&a.phikT[((size_t)bh * 64 + d) * 1024 + tpos] = P.pu;
        }
        __syncthreads();
        bf16* dst = (z == 0) ? a.phiqB : a.phikB;
        #pragma unroll
        for (int k = 0; k < 2; ++k) {
            const int idx = k * 256 + tid;
            const int row = idx >> 3, cb = (idx & 7) * 8;
            *(uint4*)&dst[((size_t)bh * 1024 + tpos0 + row) * 64 + cb] =
                *(const uint4*)&As[row * 64 + cb];
        }
    } else {
        #pragma unroll
        for (int v = 0; v < 4; ++v) {
            const int d = v * 16 + r;
            union { uint2 pu; bf16 h4[4]; } P;
            #pragma unroll
            for (int i = 0; i < 4; ++i) P.h4[i] = (bf16)acc[v][i];
            *(uint2*)&a.vbufT[((size_t)bh * 64 + d) * 1024 + tpos] = P.pu;
        }
    }
}

// ------------------------------------------------- fused scan + attention
__global__ __launch_bounds__(256) void k_attn(
        const bf16* __restrict__ phiqB, const bf16* __restrict__ phikB,
        const bf16* __restrict__ phikT, const bf16* __restrict__ vbufT,
        bf16* __restrict__ attn) {
    const int ntile = blockIdx.x, c = blockIdx.y, bh = blockIdx.z;
    __shared__ char smem[56064] __attribute__((aligned(16)));
    bf16* pqs  = (bf16*)smem;               // [64][72]
    bf16* kv0s = (bf16*)(smem + 9216);      // [64][72]  rows e over d
    bf16* Pbs  = (bf16*)smem;               // [64][136] overlay (after phase A)
    bf16* pks  = (bf16*)(smem + 18432);     // [128][72]
    bf16* vts  = (bf16*)(smem + 36864);     // [64][136]
    bf16* tB   = (bf16*)(smem + 18432);     // prefix phiK^T tile [64][136] (d x t)
    bf16* tA   = (bf16*)(smem + 36864);     // prefix V^T tile [64][136]  (e x t)
    float* kc0s = (float*)(smem + 54272);   // [64]
    float* Zrow = (float*)(smem + 54528);   // [64]
    float* Zp   = (float*)(smem + 54784);   // [4][64]
    float* Zs   = (float*)(smem + 55808);   // [64]

    const int tid = threadIdx.x;
    const int wid = tid >> 6, lane = tid & 63;
    const int q = lane >> 4, r = lane & 15;
    const size_t tbase = (size_t)bh * 1024 + c * 128;
    const int t0 = ntile * 64;

    // stage phiQ
    #pragma unroll
    for (int k = 0; k < 2; ++k) {
        const int idx = k * 256 + tid;
        const int row = idx >> 3, col = (idx & 7) * 8;
        *(uint4*)&pqs[row * 72 + col] =
            *(const uint4*)&phiqB[(tbase + t0 + row) * 64 + col];
    }

    // ---- exclusive chunk prefix via MFMA: kv0[e][d], kc0[d]
    v4f kvacc[4];
    #pragma unroll
    for (int v = 0; v < 4; ++v) kvacc[v] = (v4f){0.f, 0.f, 0.f, 0.f};
    float kcp = 0.f;
    const int srow = tid >> 2, scol = (tid & 3) * 32;
    const int kd = tid & 63, ktq = tid >> 6;
    for (int cc = 0; cc < c; ++cc) {
        __syncthreads();
        #pragma unroll
        for (int j = 0; j < 4; ++j) {
            *(uint4*)&tB[srow * 136 + scol + j * 8] =
                *(const uint4*)&phikT[((size_t)bh * 64 + srow) * 1024 + cc * 128 + scol + j * 8];
            *(uint4*)&tA[srow * 136 + scol + j * 8] =
                *(const uint4*)&vbufT[((size_t)bh * 64 + srow) * 1024 + cc * 128 + scol + j * 8];
        }
        __syncthreads();
        #pragma unroll
        for (int kk = 0; kk < 4; ++kk) {
            v8bf av = *(const v8bf*)&tA[(wid * 16 + r) * 136 + kk * 32 + q * 8];
            #pragma unroll
            for (int v = 0; v < 4; ++v) {
                v8bf bd = *(const v8bf*)&tB[(v * 16 + r) * 136 + kk * 32 + q * 8];
                kvacc[v] = __builtin_amdgcn_mfma_f32_16x16x32_bf16(av, bd, kvacc[v], 0, 0, 0);
            }
        }
        #pragma unroll
        for (int j4 = 0; j4 < 4; ++j4) {
            v8bf p = *(const v8bf*)&tB[kd * 136 + ktq * 32 + j4 * 8];
            #pragma unroll
            for (int jj = 0; jj < 8; ++jj) kcp += (float)p[jj];
        }
    }
    #pragma unroll
    for (int v = 0; v < 4; ++v)
        #pragma unroll
        for (int i = 0; i < 4; ++i)
            kv0s[(wid * 16 + q * 4 + i) * 72 + v * 16 + r] = (bf16)kvacc[v][i];
    Zp[ktq * 64 + kd] = kcp;
    __syncthreads();

    // stage phiK natural + V^T (own chunk), fold kc partials
    #pragma unroll
    for (int k = 0; k < 4; ++k) {
        const int idx = k * 256 + tid;
        const int row = idx >> 3, col = (idx & 7) * 8;
        *(uint4*)&pks[row * 72 + col] =
            *(const uint4*)&phikB[(tbase + row) * 64 + col];
        const int row2 = idx >> 4, col2 = (idx & 15) * 8;
        *(uint4*)&vts[row2 * 136 + col2] =
            *(const uint4*)&vbufT[((size_t)bh * 64 + row2) * 1024 + c * 128 + col2];
    }
    if (tid < 64)
        kc0s[tid] = Zp[tid] + Zp[64 + tid] + Zp[128 + tid] + Zp[192 + tid];
    __syncthreads();

    // ---- phase A: out1 + S MFMAs, Z0 partials
    v4f oacc[4], sacc[8];
    #pragma unroll
    for (int t = 0; t < 4; ++t) oacc[t] = (v4f){0.f, 0.f, 0.f, 0.f};
    #pragma unroll
    for (int u = 0; u < 8; ++u) sacc[u] = (v4f){0.f, 0.f, 0.f, 0.f};
    const int nmt = (ntile == 0) ? 4 : 8;

    #pragma unroll
    for (int kk = 0; kk < 2; ++kk) {
        v8bf af = *(const v8bf*)&pqs[(wid * 16 + r) * 72 + kk * 32 + q * 8];
        #pragma unroll
        for (int t = 0; t < 4; ++t) {
            v8bf bfr = *(const v8bf*)&kv0s[(t * 16 + r) * 72 + kk * 32 + q * 8];
            oacc[t] = __builtin_amdgcn_mfma_f32_16x16x32_bf16(af, bfr, oacc[t], 0, 0, 0);
        }
        #pragma unroll
        for (int u = 0; u < 8; ++u) {
            if (u < nmt) {
                v8bf bk = *(const v8bf*)&pks[(u * 16 + r) * 72 + kk * 32 + q * 8];
                sacc[u] = __builtin_amdgcn_mfma_f32_16x16x32_bf16(af, bk, sacc[u], 0, 0, 0);
            }
        }
    }
    {
        float z0 = 0.f;
        #pragma unroll
        for (int j = 0; j < 16; ++j)
            z0 += (float)pqs[lane * 72 + wid * 16 + j] * kc0s[wid * 16 + j];
        Zp[wid * 64 + lane] = z0;
    }
    __syncthreads();

    float zi[4] = {0.f, 0.f, 0.f, 0.f};
    #pragma unroll
    for (int u = 0; u < 8; ++u) {
        if (u < nmt) {
            const int m = u * 16 + r;
            #pragma unroll
            for (int i = 0; i < 4; ++i) {
                const int nloc = t0 + wid * 16 + q * 4 + i;
                const float sv = (m <= nloc) ? sacc[u][i] : 0.f;
                zi[i] += sv;
                Pbs[(wid * 16 + q * 4 + i) * 136 + m] = (bf16)sv;
            }
        }
    }
    #pragma unroll
    for (int w = 1; w < 16; w <<= 1) {
        #pragma unroll
        for (int i = 0; i < 4; ++i) zi[i] += __shfl_xor(zi[i], w);
    }
    if (r == 0) {
        #pragma unroll
        for (int i = 0; i < 4; ++i) Zrow[wid * 16 + q * 4 + i] = zi[i];
    }
    __syncthreads();

    if (tid < 64)
        Zs[tid] = fmaxf(Zrow[tid] + Zp[tid] + Zp[64 + tid] + Zp[128 + tid] + Zp[192 + tid],
                        1e-6f);
    __syncthreads();

    const int nkk = (ntile == 0) ? 2 : 4;
    #pragma unroll
    for (int kk = 0; kk < 4; ++kk) {
        if (kk < nkk) {
            v8bf af = *(const v8bf*)&Pbs[(wid * 16 + r) * 136 + kk * 32 + q * 8];
            #pragma unroll
            for (int t = 0; t < 4; ++t) {
                v8bf bfr = *(const v8bf*)&vts[(t * 16 + r) * 136 + kk * 32 + q * 8];
                oacc[t] = __builtin_amdgcn_mfma_f32_16x16x32_bf16(af, bfr, oacc[t], 0, 0, 0);
            }
        }
    }

    const int b = bh >> 3, h = bh & 7;
    #pragma unroll
    for (int t = 0; t < 4; ++t) {
        const int e = t * 16 + r;
        #pragma unroll
        for (int i = 0; i < 4; ++i) {
            const int row = wid * 16 + q * 4 + i;
            const float val = oacc[t][i] / Zs[row];
            const size_t mtok = (size_t)b * 1024 + c * 128 + t0 + row;
            attn[mtok * 512 + h * 64 + e] = (bf16)val;
        }
    }
}

// ------------------------------------------------- output projection (f32 out)
struct OArgs { const bf16* attn; const float* wo; const float* partial;
               const float* bo; float* y; };

__global__ __launch_bounds__(256) void k_oproj(OArgs a) {
    __shared__ bf16 As[64 * 64] __attribute__((aligned(16)));
    __shared__ bf16 Bs[64 * 64] __attribute__((aligned(16)));
    const float s = alpha_scale(a.partial, 3);
    const float inv_s = 1.f / s;
    v4f acc[4];
    #pragma unroll
    for (int v = 0; v < 4; ++v) acc[v] = (v4f){0.f, 0.f, 0.f, 0.f};
    gemm64_bf16A((const char*)(a.attn + (size_t)(blockIdx.x * 64) * 512),
                 a.wo + (size_t)(blockIdx.y * 64) * 512,
                 s, inv_s, As, Bs, acc);

    const int tid = threadIdx.x;
    const int wm = tid >> 6, lane = tid & 63;
    const int q = lane >> 4, r = lane & 15;
    #pragma unroll
    for (int v = 0; v < 4; ++v) {
        const int n = blockIdx.y * 64 + v * 16 + r;
        const float bias = a.bo[n];
        #pragma unroll
        for (int i = 0; i < 4; ++i) {
            const int m = blockIdx.x * 64 + wm * 16 + q * 4 + i;
            a.y[(size_t)m * 512 + n] = acc[v][i] + bias;
        }
    }
}

// ---------------------------------------------------------------- launch
extern "C" void kernel_launch(void* const* d_in, const int* in_sizes, int n_in,
                              void* d_out, int out_size, void* d_ws, size_t ws_size,
                              hipStream_t stream) {
    const float* x   = (const float*)d_in[0];
    const float* Wq  = (const float*)d_in[1];
    const float* Wk  = (const float*)d_in[2];
    const float* Wv  = (const float*)d_in[3];
    const float* Wo  = (const float*)d_in[4];
    const float* bo  = (const float*)d_in[5];
    const float* tab = (const float*)d_in[6];

    uint8_t* w = (uint8_t*)d_ws;
    bf16* phiqB  = (bf16*)w;                                  // 2 MB
    bf16* phikB  = phiqB + (size_t)16 * 1024 * 64;            // 2 MB
    bf16* phikT  = phikB + (size_t)16 * 1024 * 64;            // 2 MB
    bf16* vbufT  = phikT + (size_t)16 * 64 * 1024;            // 2 MB
    bf16* attn   = vbufT + (size_t)16 * 64 * 1024;            // 2 MB
    float* partial = (float*)(attn + (size_t)2048 * 512);     // 256 f32

    AlphaArgs aa;
    aa.w[0] = Wq; aa.w[1] = Wk; aa.w[2] = Wv; aa.w[3] = Wo;
    aa.partial = partial;
    k_alpha<<<dim3(256), dim3(256), 0, stream>>>(aa);

    QkvArgs pa;
    pa.x = x; pa.w[0] = Wq; pa.w[1] = Wk; pa.w[2] = Wv;
    pa.partial = partial; pa.table = tab;
    pa.phiqB = phiqB; pa.phikB = phikB; pa.phikT = phikT; pa.vbufT = vbufT;
    k_qkv<<<dim3(32, 24), dim3(256), 0, stream>>>(pa);

    k_attn<<<dim3(2, NCHUNK, BH), dim3(256), 0, stream>>>(phiqB, phikB, phikT, vbufT, attn);

    OArgs oa{ attn, Wo, partial, bo, (float*)d_out };
    k_oproj<<<dim3(32, 8), dim3(256), 0, stream>>>(oa);
}

// Round 10
// 103.380 us; speedup vs baseline: 1.0729x; 1.0729x over previous
//
#include <hip/hip_runtime.h>
#include <stdint.h>

typedef __bf16 bf16;
typedef __bf16 v8bf __attribute__((ext_vector_type(8)));
typedef float v4f __attribute__((ext_vector_type(4)));

#define T_SEQ   1024
#define D_MODEL 512
#define N_HEADS 8
#define D_HEAD  64
#define B_SZ    2
#define BH      (B_SZ * N_HEADS)     // 16
#define CHUNK   128
#define NCHUNK  (T_SEQ / CHUNK)      // 8
#define WN      (D_MODEL * D_MODEL)  // 262144

// async global->LDS, 16B per lane; LDS dest is wave-uniform base + lane*16
__device__ __forceinline__ void lds16(const void* g, void* l) {
    __builtin_amdgcn_global_load_lds(
        (const __attribute__((address_space(1))) uint32_t*)g,
        (__attribute__((address_space(3))) uint32_t*)l, 16, 0, 0);
}

// ------------------------------------------------- fused alpha-reduce + x cast
struct PreArgs { const float* w[4]; float* partial; const float* x; bf16* xb; };

__global__ __launch_bounds__(256) void k_pre(PreArgs a) {
    const int bid = blockIdx.x, tid = threadIdx.x;
    if (bid < 256) {
        const int mid = bid >> 6, blk = bid & 63;
        const float* __restrict__ W = a.w[mid];
        float sabs = 0.f;
        #pragma unroll
        for (int k = 0; k < 4; ++k) {
            float4 v = ((const float4*)W)[blk * 1024 + k * 256 + tid];
            sabs += fabsf(v.x) + fabsf(v.y) + fabsf(v.z) + fabsf(v.w);
        }
        __shared__ float red[256];
        red[tid] = sabs;
        __syncthreads();
        for (int s = 128; s > 0; s >>= 1) {
            if (tid < s) red[tid] += red[tid + s];
            __syncthreads();
        }
        if (tid == 0) a.partial[mid * 64 + blk] = red[0];
    } else {
        const int i = (bid - 256) * 256 + tid;    // float4 index, 262144 total
        float4 v = ((const float4*)a.x)[i];
        union { uint2 u; bf16 h[4]; } H;
        H.h[0] = (bf16)v.x; H.h[1] = (bf16)v.y;
        H.h[2] = (bf16)v.z; H.h[3] = (bf16)v.w;
        ((uint2*)a.xb)[i] = H.u;
    }
}

// ------------------------------------------------- weight quantize
struct WqArgs { const float* w[4]; bf16* wt[4]; const float* partial; };

__global__ __launch_bounds__(256) void k_wquant(WqArgs a) {
    const int mid = blockIdx.y, blk = blockIdx.x, tid = threadIdx.x;
    const float* __restrict__ W = a.w[mid];
    bf16* __restrict__ Wt = a.wt[mid];
    __shared__ float sv;
    if (tid < 64) {
        float p = a.partial[mid * 64 + tid];
        #pragma unroll
        for (int w = 1; w < 64; w <<= 1) p += __shfl_xor(p, w);
        if (tid == 0) {
            float alpha = p / (float)WN + 1e-12f;
            float e = rintf(log2f(alpha));
            e = fminf(4.f, fmaxf(-4.f, e));
            sv = exp2f(e);
        }
    }
    __syncthreads();
    const float s = sv;
    const float inv_s = 1.f / s;              // s is a power of two: exact
    #pragma unroll
    for (int k = 0; k < 4; ++k) {
        const int idx = blk * 1024 + k * 256 + tid;
        float4 v = ((const float4*)W)[idx];
        float vv[4] = {v.x, v.y, v.z, v.w};
        union { uint2 u; bf16 h[4]; } o;
        #pragma unroll
        for (int j = 0; j < 4; ++j) {
            float r = rintf(vv[j] * inv_s);
            r = fminf(1.f, fmaxf(-1.f, r));
            o.h[j] = (bf16)(r * s);
        }
        ((uint2*)Wt)[idx] = o.u;
    }
}

// ------------------------------------------------- 64x64 swizzled GEMM core
// C(64x64) = A[64][512] @ B[64][512]^T (NT), K=512, BK=64, global_load_lds w16.
// XOR-swizzled LDS: phys 16B chunk = logical ^ (row&7), applied on the global
// source address (dest must stay base+lane*16).
__device__ __forceinline__ void gemm64(
        const char* __restrict__ Ab, const char* __restrict__ Bb,
        bf16* As, bf16* Bs, v4f acc[4]) {
    const int tid = threadIdx.x;
    const int wm = tid >> 6, lane = tid & 63;
    const int q = lane >> 4, r = lane & 15;
    const int lrow = lane >> 3;               // 0..7
    const int schunk = (lane & 7) ^ lrow;     // swizzled source chunk
    const int r7 = r & 7;

    for (int k0 = 0; k0 < 512; k0 += 64) {
        #pragma unroll
        for (int j = 0; j < 2; ++j) {
            const int seg = wm * 2 + j;       // 8 segs over 4 waves
            const int row = seg * 8 + lrow;
            const size_t goff = (size_t)row * 1024 + (size_t)k0 * 2 + schunk * 16;
            lds16(Ab + goff, (char*)As + (seg << 10));
            lds16(Bb + goff, (char*)Bs + (seg << 10));
        }
        __syncthreads();
        #pragma unroll
        for (int s = 0; s < 2; ++s) {
            const int co = ((s * 4 + q) ^ r7) * 8;     // swizzled read chunk
            v8bf ah = *(const v8bf*)&As[(wm * 16 + r) * 64 + co];
            v8bf bb[4];
            #pragma unroll
            for (int v = 0; v < 4; ++v)
                bb[v] = *(const v8bf*)&Bs[(v * 16 + r) * 64 + co];
            #pragma unroll
            for (int v = 0; v < 4; ++v)
                acc[v] = __builtin_amdgcn_mfma_f32_16x16x32_bf16(ah, bb[v], acc[v], 0, 0, 0);
        }
        __syncthreads();
    }
}

// ------------------------------------------------- fused QKV GEMM (+phi)
// Wstk rows: 0-511=Wq, 512-1023=Wk, 1024-1535=Wv. tn 0..23, z = tn>>3, h = tn&7.
struct Qkv2Args {
    const bf16* xb; const bf16* wstk;
    const float* table;
    bf16* phiqB; bf16* phikB; bf16* phikT; bf16* vbufT;
};

__global__ __launch_bounds__(256) void k_qkv2(Qkv2Args a) {
    __shared__ bf16 As[64 * 64] __attribute__((aligned(16)));
    __shared__ bf16 Bs[64 * 64] __attribute__((aligned(16)));
    __shared__ float tab[512];
    const int tid = threadIdx.x;
    const int tm = blockIdx.x, tn = blockIdx.y;
    const int z = tn >> 3;
    if (z < 2) { tab[tid] = a.table[tid]; tab[tid + 256] = a.table[tid + 256]; }

    v4f acc[4];
    #pragma unroll
    for (int v = 0; v < 4; ++v) acc[v] = (v4f){0.f, 0.f, 0.f, 0.f};

    gemm64((const char*)(a.xb + (size_t)(tm * 64) * 512),
           (const char*)(a.wstk + (size_t)(tn * 64) * 512), As, Bs, acc);

    const int wm = tid >> 6, lane = tid & 63;
    const int q = lane >> 4, r = lane & 15;
    const int h = tn & 7;
    const int mb = tm * 64;
    const int b = mb >> 10, tpos0 = mb & 1023;     // 64 rows stay in one b
    const int bh = b * 8 + h;
    const int tpos = tpos0 + wm * 16 + q * 4;      // this thread's 4 tokens

    if (z < 2) {
        // phi, write LDS (for transposed natural store), K also direct [d][t]
        #pragma unroll
        for (int v = 0; v < 4; ++v) {
            const int d = v * 16 + r;
            union { uint2 pu; bf16 h4[4]; } P;
            #pragma unroll
            for (int i = 0; i < 4; ++i) {
                float val = acc[v][i];
                int i0 = (int)rintf(val / 0.1f) + 128;
                i0 = min(255, max(0, i0));
                int i1 = (int)rintf(val / 0.2f) + 128;
                i1 = min(255, max(0, i1));
                val = tab[i0] + tab[256 + i1];
                As[(wm * 16 + q * 4 + i) * 64 + d] = (bf16)val;
                P.h4[i] = (bf16)val;
            }
            if (z == 1)
                *(uint2*)&a.phikT[((size_t)bh * 64 + d) * 1024 + tpos] = P.pu;
        }
        __syncthreads();
        bf16* dst = (z == 0) ? a.phiqB : a.phikB;
        #pragma unroll
        for (int k = 0; k < 2; ++k) {
            const int idx = k * 256 + tid;
            const int row = idx >> 3, cb = (idx & 7) * 8;
            *(uint4*)&dst[((size_t)bh * 1024 + tpos0 + row) * 64 + cb] =
                *(const uint4*)&As[row * 64 + cb];
        }
    } else {
        #pragma unroll
        for (int v = 0; v < 4; ++v) {
            const int d = v * 16 + r;
            union { uint2 pu; bf16 h4[4]; } P;
            #pragma unroll
            for (int i = 0; i < 4; ++i) P.h4[i] = (bf16)acc[v][i];
            *(uint2*)&a.vbufT[((size_t)bh * 64 + d) * 1024 + tpos] = P.pu;
        }
    }
}

// ------------------------------------------------- per-chunk kv + ksum (MFMA)
// Block (c, bh): kvT[bh][c][e*64+d] = sum_t V[e][t] phiK[d][t]; ksc[bh][c][d].
__global__ __launch_bounds__(256) void k_chunkmm(
        const bf16* __restrict__ phikT, const bf16* __restrict__ vbufT,
        float* __restrict__ kvT, float* __restrict__ ksc) {
    const int c = blockIdx.x, bh = blockIdx.y;
    __shared__ bf16 tB[64 * 136] __attribute__((aligned(16)));   // phiK^T [d][t]
    __shared__ bf16 tA[64 * 136] __attribute__((aligned(16)));   // V^T   [e][t]
    __shared__ float kcr[256];
    const int tid = threadIdx.x;
    const int wid = tid >> 6, lane = tid & 63;
    const int q = lane >> 4, r = lane & 15;
    const int srow = tid >> 2, scol = (tid & 3) * 32;

    #pragma unroll
    for (int j = 0; j < 4; ++j) {
        *(uint4*)&tB[srow * 136 + scol + j * 8] =
            *(const uint4*)&phikT[((size_t)bh * 64 + srow) * 1024 + c * 128 + scol + j * 8];
        *(uint4*)&tA[srow * 136 + scol + j * 8] =
            *(const uint4*)&vbufT[((size_t)bh * 64 + srow) * 1024 + c * 128 + scol + j * 8];
    }
    __syncthreads();

    v4f kvacc[4];
    #pragma unroll
    for (int v = 0; v < 4; ++v) kvacc[v] = (v4f){0.f, 0.f, 0.f, 0.f};
    #pragma unroll
    for (int kk = 0; kk < 4; ++kk) {
        v8bf av = *(const v8bf*)&tA[(wid * 16 + r) * 136 + kk * 32 + q * 8];
        #pragma unroll
        for (int v = 0; v < 4; ++v) {
            v8bf bd = *(const v8bf*)&tB[(v * 16 + r) * 136 + kk * 32 + q * 8];
            kvacc[v] = __builtin_amdgcn_mfma_f32_16x16x32_bf16(av, bd, kvacc[v], 0, 0, 0);
        }
    }
    {   // phiK column sums over t (per-quarter partials, then reduce)
        float kcp = 0.f;
        const int kd = tid & 63, ktq = tid >> 6;
        #pragma unroll
        for (int j4 = 0; j4 < 4; ++j4) {
            v8bf p = *(const v8bf*)&tB[kd * 136 + ktq * 32 + j4 * 8];
            #pragma unroll
            for (int jj = 0; jj < 8; ++jj) kcp += (float)p[jj];
        }
        kcr[ktq * 64 + kd] = kcp;
    }
    __syncthreads();
    const size_t ob = ((size_t)bh * 8 + c) * 4096;
    #pragma unroll
    for (int v = 0; v < 4; ++v)
        #pragma unroll
        for (int i = 0; i < 4; ++i)
            kvT[ob + (size_t)(wid * 16 + q * 4 + i) * 64 + v * 16 + r] = kvacc[v][i];
    if (tid < 64)
        ksc[((size_t)bh * 8 + c) * 64 + tid] =
            kcr[tid] + kcr[64 + tid] + kcr[128 + tid] + kcr[192 + tid];
}

// ------------------------------------------------- intra-chunk attention (MFMA)
// Prefix from per-chunk sums (parallel f32 tile adds), then MFMA phases.
__global__ __launch_bounds__(256) void k_attn(
        const bf16* __restrict__ phiqB, const bf16* __restrict__ phikB,
        const bf16* __restrict__ vbufT, const float* __restrict__ kvT,
        const float* __restrict__ ksc, bf16* __restrict__ attn) {
    const int ntile = blockIdx.x, c = blockIdx.y, bh = blockIdx.z;
    __shared__ char smem[56064] __attribute__((aligned(16)));
    bf16* pqs  = (bf16*)smem;               // [64][72]
    bf16* kv0s = (bf16*)(smem + 9216);      // [64][72]  rows e over d
    bf16* Pbs  = (bf16*)smem;               // [64][136] overlay (after phase A)
    bf16* pks  = (bf16*)(smem + 18432);     // [128][72]
    bf16* vts  = (bf16*)(smem + 36864);     // [64][136]
    float* kc0s = (float*)(smem + 54272);   // [64]
    float* Zrow = (float*)(smem + 54528);   // [64]
    float* Zp   = (float*)(smem + 54784);   // [4][64]
    float* Zs   = (float*)(smem + 55808);   // [64]

    const int tid = threadIdx.x;
    const int wid = tid >> 6, lane = tid & 63;
    const int q = lane >> 4, r = lane & 15;
    const size_t tbase = (size_t)bh * 1024 + c * 128;
    const int t0 = ntile * 64;

    // stage phiQ
    #pragma unroll
    for (int k = 0; k < 2; ++k) {
        const int idx = k * 256 + tid;
        const int row = idx >> 3, col = (idx & 7) * 8;
        *(uint4*)&pqs[row * 72 + col] =
            *(const uint4*)&phiqB[(tbase + t0 + row) * 64 + col];
    }
    {   // exclusive kv chunk-prefix -> kv0s bf16 [e][d]
        const int e = tid >> 2, db = (tid & 3) * 16;
        float accp[16];
        #pragma unroll
        for (int j = 0; j < 16; ++j) accp[j] = 0.f;
        for (int cc = 0; cc < c; ++cc) {
            const float* src = kvT + ((size_t)bh * 8 + cc) * 4096 + e * 64 + db;
            #pragma unroll
            for (int k4 = 0; k4 < 4; ++k4) {
                float4 f = *(const float4*)(src + 4 * k4);
                accp[4 * k4]     += f.x; accp[4 * k4 + 1] += f.y;
                accp[4 * k4 + 2] += f.z; accp[4 * k4 + 3] += f.w;
            }
        }
        union { uint4 u; bf16 h8[8]; } U0, U1;
        #pragma unroll
        for (int j = 0; j < 8; ++j) {
            U0.h8[j] = (bf16)accp[j];
            U1.h8[j] = (bf16)accp[8 + j];
        }
        *(uint4*)&kv0s[e * 72 + db] = U0.u;
        *(uint4*)&kv0s[e * 72 + db + 8] = U1.u;
    }
    // stage phiK natural + V^T (own chunk)
    #pragma unroll
    for (int k = 0; k < 4; ++k) {
        const int idx = k * 256 + tid;
        const int row = idx >> 3, col = (idx & 7) * 8;
        *(uint4*)&pks[row * 72 + col] =
            *(const uint4*)&phikB[(tbase + row) * 64 + col];
        const int row2 = idx >> 4, col2 = (idx & 15) * 8;
        *(uint4*)&vts[row2 * 136 + col2] =
            *(const uint4*)&vbufT[((size_t)bh * 64 + row2) * 1024 + c * 128 + col2];
    }
    if (tid < 64) {   // exclusive k-sum prefix from raw per-chunk sums
        float s = 0.f;
        for (int cc = 0; cc < c; ++cc) s += ksc[((size_t)bh * 8 + cc) * 64 + tid];
        kc0s[tid] = s;
    }
    __syncthreads();

    // ---- phase A: out1 + S MFMAs, Z0 partials
    v4f oacc[4], sacc[8];
    #pragma unroll
    for (int t = 0; t < 4; ++t) oacc[t] = (v4f){0.f, 0.f, 0.f, 0.f};
    #pragma unroll
    for (int u = 0; u < 8; ++u) sacc[u] = (v4f){0.f, 0.f, 0.f, 0.f};
    const int nmt = (ntile == 0) ? 4 : 8;

    #pragma unroll
    for (int kk = 0; kk < 2; ++kk) {
        v8bf af = *(const v8bf*)&pqs[(wid * 16 + r) * 72 + kk * 32 + q * 8];
        #pragma unroll
        for (int t = 0; t < 4; ++t) {
            v8bf bfr = *(const v8bf*)&kv0s[(t * 16 + r) * 72 + kk * 32 + q * 8];
            oacc[t] = __builtin_amdgcn_mfma_f32_16x16x32_bf16(af, bfr, oacc[t], 0, 0, 0);
        }
        #pragma unroll
        for (int u = 0; u < 8; ++u) {
            if (u < nmt) {
                v8bf bk = *(const v8bf*)&pks[(u * 16 + r) * 72 + kk * 32 + q * 8];
                sacc[u] = __builtin_amdgcn_mfma_f32_16x16x32_bf16(af, bk, sacc[u], 0, 0, 0);
            }
        }
    }
    {
        float z0 = 0.f;
        #pragma unroll
        for (int j = 0; j < 16; ++j)
            z0 += (float)pqs[lane * 72 + wid * 16 + j] * kc0s[wid * 16 + j];
        Zp[wid * 64 + lane] = z0;
    }
    __syncthreads();   // pqs/kv0s dead; Pbs overlay OK

    // ---- mask, rowsum, write P
    float zi[4] = {0.f, 0.f, 0.f, 0.f};
    #pragma unroll
    for (int u = 0; u < 8; ++u) {
        if (u < nmt) {
            const int m = u * 16 + r;
            #pragma unroll
            for (int i = 0; i < 4; ++i) {
                const int nloc = t0 + wid * 16 + q * 4 + i;
                const float sv = (m <= nloc) ? sacc[u][i] : 0.f;
                zi[i] += sv;
                Pbs[(wid * 16 + q * 4 + i) * 136 + m] = (bf16)sv;
            }
        }
    }
    #pragma unroll
    for (int w = 1; w < 16; w <<= 1) {
        #pragma unroll
        for (int i = 0; i < 4; ++i) zi[i] += __shfl_xor(zi[i], w);
    }
    if (r == 0) {
        #pragma unroll
        for (int i = 0; i < 4; ++i) Zrow[wid * 16 + q * 4 + i] = zi[i];
    }
    __syncthreads();

    if (tid < 64)
        Zs[tid] = fmaxf(Zrow[tid] + Zp[tid] + Zp[64 + tid] + Zp[128 + tid] + Zp[192 + tid],
                        1e-6f);
    __syncthreads();

    // ---- phase B: out += P @ V
    const int nkk = (ntile == 0) ? 2 : 4;
    #pragma unroll
    for (int kk = 0; kk < 4; ++kk) {
        if (kk < nkk) {
            v8bf af = *(const v8bf*)&Pbs[(wid * 16 + r) * 136 + kk * 32 + q * 8];
            #pragma unroll
            for (int t = 0; t < 4; ++t) {
                v8bf bfr = *(const v8bf*)&vts[(t * 16 + r) * 136 + kk * 32 + q * 8];
                oacc[t] = __builtin_amdgcn_mfma_f32_16x16x32_bf16(af, bfr, oacc[t], 0, 0, 0);
            }
        }
    }

    const int b = bh >> 3, h = bh & 7;
    #pragma unroll
    for (int t = 0; t < 4; ++t) {
        const int e = t * 16 + r;
        #pragma unroll
        for (int i = 0; i < 4; ++i) {
            const int row = wid * 16 + q * 4 + i;
            const float val = oacc[t][i] / Zs[row];
            const size_t mtok = (size_t)b * 1024 + c * 128 + t0 + row;
            attn[mtok * 512 + h * 64 + e] = (bf16)val;
        }
    }
}

// ------------------------------------------------- output projection (f32 out)
struct OArgs { const bf16* attn; const bf16* wo; const float* bo; float* y; };

__global__ __launch_bounds__(256) void k_oproj(OArgs a) {
    __shared__ bf16 As[64 * 64] __attribute__((aligned(16)));
    __shared__ bf16 Bs[64 * 64] __attribute__((aligned(16)));
    v4f acc[4];
    #pragma unroll
    for (int v = 0; v < 4; ++v) acc[v] = (v4f){0.f, 0.f, 0.f, 0.f};
    gemm64((const char*)(a.attn + (size_t)(blockIdx.x * 64) * 512),
           (const char*)(a.wo + (size_t)(blockIdx.y * 64) * 512), As, Bs, acc);

    const int tid = threadIdx.x;
    const int wm = tid >> 6, lane = tid & 63;
    const int q = lane >> 4, r = lane & 15;
    #pragma unroll
    for (int v = 0; v < 4; ++v) {
        const int n = blockIdx.y * 64 + v * 16 + r;
        const float bias = a.bo[n];
        #pragma unroll
        for (int i = 0; i < 4; ++i) {
            const int m = blockIdx.x * 64 + wm * 16 + q * 4 + i;
            a.y[(size_t)m * 512 + n] = acc[v][i] + bias;
        }
    }
}

// ---------------------------------------------------------------- launch
extern "C" void kernel_launch(void* const* d_in, const int* in_sizes, int n_in,
                              void* d_out, int out_size, void* d_ws, size_t ws_size,
                              hipStream_t stream) {
    const float* x   = (const float*)d_in[0];
    const float* Wq  = (const float*)d_in[1];
    const float* Wk  = (const float*)d_in[2];
    const float* Wv  = (const float*)d_in[3];
    const float* Wo  = (const float*)d_in[4];
    const float* bo  = (const float*)d_in[5];
    const float* tab = (const float*)d_in[6];

    uint8_t* w = (uint8_t*)d_ws;
    bf16* wt     = (bf16*)w;                                  // 2 MB [Wq;Wk;Wv;Wo]
    bf16* xb     = wt + 4 * WN;                               // 2 MB
    bf16* phiqB  = xb + 1048576;                              // 2 MB
    bf16* phikB  = phiqB + (size_t)16 * 1024 * 64;            // 2 MB
    bf16* phikT  = phikB + (size_t)16 * 1024 * 64;            // 2 MB
    bf16* vbufT  = phikT + (size_t)16 * 64 * 1024;            // 2 MB
    bf16* attn   = vbufT + (size_t)16 * 64 * 1024;            // 2 MB
    float* kvT   = (float*)(attn + (size_t)2048 * 512);       // 2 MB
    float* ksc   = kvT + (size_t)16 * 8 * 4096;               // 32 KB
    float* partial = ksc + 16 * 8 * 64;                       // 256 f32

    PreArgs pr;
    pr.w[0] = Wq; pr.w[1] = Wk; pr.w[2] = Wv; pr.w[3] = Wo;
    pr.partial = partial; pr.x = x; pr.xb = xb;
    k_pre<<<dim3(1280), dim3(256), 0, stream>>>(pr);

    WqArgs qa;
    qa.w[0] = Wq; qa.w[1] = Wk; qa.w[2] = Wv; qa.w[3] = Wo;
    qa.wt[0] = wt; qa.wt[1] = wt + WN; qa.wt[2] = wt + 2 * WN; qa.wt[3] = wt + 3 * WN;
    qa.partial = partial;
    k_wquant<<<dim3(64, 4), dim3(256), 0, stream>>>(qa);

    Qkv2Args pa{ xb, wt, tab, phiqB, phikB, phikT, vbufT };
    k_qkv2<<<dim3(32, 24), dim3(256), 0, stream>>>(pa);

    k_chunkmm<<<dim3(NCHUNK, BH), dim3(256), 0, stream>>>(phikT, vbufT, kvT, ksc);
    k_attn<<<dim3(2, NCHUNK, BH), dim3(256), 0, stream>>>(phiqB, phikB, vbufT, kvT, ksc, attn);

    OArgs oa{ attn, wt + 3 * WN, bo, (float*)d_out };
    k_oproj<<<dim3(32, 8), dim3(256), 0, stream>>>(oa);
}